// Round 8
// baseline (257.937 us; speedup 1.0000x reference)
//
#include <hip/hip_runtime.h>
#include <hip/hip_bf16.h>
#include <hip/hip_fp16.h>

#define T_DIM 2048
#define B_DIM 32
#define LIS_DIM 1024
#define SPE_DIM 1024
#define ATT_DIM 512

typedef _Float16 f16x8 __attribute__((ext_vector_type(8)));
typedef _Float16 f16x4 __attribute__((ext_vector_type(4)));
typedef float f32x4 __attribute__((ext_vector_type(4)));

// K0: pack W into MFMA-fragment order:
// WTf_f16x8[((mat*32+ct)*32+ks)*64 + lane] : h[j] = W[ks*32+hi*8+j][ct*16+lo]
__global__ void transpose_w_kernel(const float* __restrict__ Ws,
                                   const float* __restrict__ Wv,
                                   _Float16* __restrict__ WTf) {
  __shared__ float t17[1024 * 17];
  int blk = blockIdx.x;             // 64 = mat(2) x ct(32)
  int mat = blk >> 5, ct = blk & 31;
  int tid = threadIdx.x;
  const float* W = mat ? Wv : Ws;
  for (int e = tid; e < 16384; e += 256) {
    int k = e >> 4, c = e & 15;
    t17[k * 17 + c] = W[(size_t)k * ATT_DIM + ct * 16 + c];
  }
  __syncthreads();
  int wv4 = tid >> 6, lane = tid & 63, lo = lane & 15, hi = lane >> 4;
  for (int ks = wv4; ks < 32; ks += 4) {
    f16x8 h;
#pragma unroll
    for (int j = 0; j < 8; ++j)
      h[j] = (_Float16)t17[(ks * 32 + hi * 8 + j) * 17 + lo];
    ((f16x8*)WTf)[((size_t)((mat * 32 + ct) * 32 + ks)) * 64 + lane] = h;
  }
}

// K1: q[b][a] = relu(spe[b]·W_proj[:,a] + b_proj[a]), f32
__global__ void query_kernel(const float* __restrict__ spe,
                             const float* __restrict__ Wp,
                             const float* __restrict__ bp,
                             float* __restrict__ q) {
  __shared__ float s[SPE_DIM];
  int b = blockIdx.x;
  for (int i = threadIdx.x; i < SPE_DIM; i += 256) s[i] = spe[(size_t)b * SPE_DIM + i];
  __syncthreads();
  for (int a = threadIdx.x; a < ATT_DIM; a += 256) {
    float acc = bp[a];
    for (int l = 0; l < SPE_DIM; ++l)
      acc = fmaf(s[l], Wp[(size_t)l * ATT_DIM + a], acc);
    q[(size_t)b * ATT_DIM + a] = fmaxf(acc, 0.f);
  }
}

// K2: dual GEMM + flash-style partial epilogue. One block = (b, 64 t's).
// Computes masked scores for its 64 t (written to ws), per-block softmax
// partials (M_b, Z_b) and the weighted-vals partial N_b[512] — vals never
// leave registers.
__global__ __launch_bounds__(512, 2)
void dual_gemm_kernel(const float* __restrict__ x,
                      const _Float16* __restrict__ WTf,
                      const float* __restrict__ bs,
                      const float* __restrict__ bv,
                      const float* __restrict__ q,
                      const int* __restrict__ llen,
                      float* __restrict__ scores,   // masked, [32][2048]
                      float* __restrict__ partM,    // [32][32]
                      float* __restrict__ partZ,    // [32][32]
                      float* __restrict__ Npart) {  // [32][32][512]
  __shared__ __align__(16) char A_lds[2][16384];  // 64 rows x 128k f16, XOR swz
  __shared__ float bk_s[ATT_DIM], bv_s[ATT_DIM], q_s[ATT_DIM];
  __shared__ float red_s[64];
  __shared__ float pb_s[64];

  const int tid = threadIdx.x;
  const int blk = blockIdx.x;
  const int b = blk & 31;
  const int tc = blk >> 5;
  const int t0 = tc * 64;
  const int L = llen[b];

  bk_s[tid] = bs[tid];
  bv_s[tid] = bv[tid];
  q_s[tid] = q[(size_t)b * ATT_DIM + tid];
  if (tid < 64) red_s[tid] = 0.f;

  const float* xb = x + (size_t)b * LIS_DIM;
  const int wv = tid >> 6;
  const int lane = tid & 63;
  const int lo = lane & 15;
  const int hi = lane >> 4;

  f32x4 sl[4];  // in-flight stage registers
  auto stage_load = [&](int c) {
    const int k0 = c * 128;
#pragma unroll
    for (int it = 0; it < 4; ++it) {
      int idx = it * 512 + tid;
      int row = idx >> 5;
      int c4 = idx & 31;
      sl[it] = __builtin_nontemporal_load(
          (const f32x4*)(xb + (size_t)(t0 + row) * (B_DIM * LIS_DIM) + k0) + c4);
    }
  };
  auto stage_write = [&](int c) {
    char* buf = A_lds[c & 1];
#pragma unroll
    for (int it = 0; it < 4; ++it) {
      int idx = it * 512 + tid;
      int row = idx >> 5;
      int c4 = idx & 31;
      f16x4 h;
      h[0] = (_Float16)sl[it][0]; h[1] = (_Float16)sl[it][1];
      h[2] = (_Float16)sl[it][2]; h[3] = (_Float16)sl[it][3];
      int off = (row * 256 + c4 * 8) ^ ((row & 7) << 4);
      *(f16x4*)(buf + off) = h;
    }
  };

  f32x4 kacc[4][4], vacc[4][4];
#pragma unroll
  for (int m = 0; m < 4; ++m)
#pragma unroll
    for (int n = 0; n < 4; ++n) {
      kacc[m][n] = (f32x4){0.f, 0.f, 0.f, 0.f};
      vacc[m][n] = (f32x4){0.f, 0.f, 0.f, 0.f};
    }

  stage_load(0);
  stage_write(0);
  __syncthreads();

  const f16x8* Wf = (const f16x8*)WTf;
  f16x8 wkf[2][4], wvf[2][4];  // register double-buffer for W frags
#pragma unroll
  for (int n = 0; n < 4; ++n) {
    wkf[0][n] = Wf[(size_t)((wv * 4 + n) * 32 + 0) * 64 + lane];
    wvf[0][n] = Wf[(size_t)((32 + wv * 4 + n) * 32 + 0) * 64 + lane];
  }

  for (int c = 0; c < 8; ++c) {
    if (c < 7) stage_load(c + 1);
    const char* buf = A_lds[c & 1];
#pragma unroll
    for (int kki = 0; kki < 4; ++kki) {
      const int ks = c * 4 + kki;
      const int kp = (ks + 1 < 32) ? ks + 1 : 31;
      const int cur = kki & 1, nxt = cur ^ 1;
#pragma unroll
      for (int n = 0; n < 4; ++n) {
        wkf[nxt][n] = Wf[(size_t)((wv * 4 + n) * 32 + kp) * 64 + lane];
        wvf[nxt][n] = Wf[(size_t)((32 + wv * 4 + n) * 32 + kp) * 64 + lane];
      }
      f16x8 bx[4];
#pragma unroll
      for (int m = 0; m < 4; ++m) {
        int row = m * 16 + lo;
        int off = (row * 256 + kki * 64 + hi * 16) ^ ((row & 7) << 4);
        bx[m] = *(const f16x8*)(buf + off);
      }
#pragma unroll
      for (int n = 0; n < 4; ++n)
#pragma unroll
        for (int m = 0; m < 4; ++m) {
          kacc[m][n] = __builtin_amdgcn_mfma_f32_16x16x32_f16(wkf[cur][n], bx[m], kacc[m][n], 0, 0, 0);
          vacc[m][n] = __builtin_amdgcn_mfma_f32_16x16x32_f16(wvf[cur][n], bx[m], vacc[m][n], 0, 0, 0);
        }
    }
    if (c < 7) stage_write(c + 1);
    __syncthreads();
  }

  // scores epilogue: per-t dot with q, reduce across cols
  float sr[4] = {0.f, 0.f, 0.f, 0.f};
#pragma unroll
  for (int m = 0; m < 4; ++m)
#pragma unroll
    for (int n = 0; n < 4; ++n) {
      int col = wv * 64 + n * 16 + hi * 4;
#pragma unroll
      for (int r = 0; r < 4; ++r)
        sr[m] += q_s[col + r] * fmaxf(kacc[m][n][r] + bk_s[col + r], 0.f);
    }
#pragma unroll
  for (int m = 0; m < 4; ++m) {
    sr[m] += __shfl_xor(sr[m], 16, 64);
    sr[m] += __shfl_xor(sr[m], 32, 64);
    if (lane < 16) atomicAdd(&red_s[m * 16 + lo], sr[m]);
  }
  __syncthreads();

  // wave 0: mask scores, write them, compute block softmax partials
  if (wv == 0) {
    float s = red_s[lane] + ((t0 + lane) >= L ? -100.f : 0.f);
    scores[(size_t)b * T_DIM + t0 + lane] = s;
    float mx = s;
#pragma unroll
    for (int d = 1; d < 64; d <<= 1) mx = fmaxf(mx, __shfl_xor(mx, d, 64));
    float p = expf(s - mx);
    float z = p;
#pragma unroll
    for (int d = 1; d < 64; d <<= 1) z += __shfl_xor(z, d, 64);
    pb_s[lane] = p;
    if (lane == 0) {
      partM[b * 32 + tc] = mx;
      partZ[b * 32 + tc] = z;
    }
  }
  __syncthreads();

  // weighted vals partial: N_b[col] = sum_t p[t] * relu(vals[t][col])
  float cs[4][4] = {};
#pragma unroll
  for (int m = 0; m < 4; ++m) {
    float p = pb_s[m * 16 + lo];
#pragma unroll
    for (int n = 0; n < 4; ++n) {
      int col = wv * 64 + n * 16 + hi * 4;
#pragma unroll
      for (int r = 0; r < 4; ++r)
        cs[n][r] += p * fmaxf(vacc[m][n][r] + bv_s[col + r], 0.f);
    }
  }
#pragma unroll
  for (int n = 0; n < 4; ++n)
#pragma unroll
    for (int r = 0; r < 4; ++r) {
      cs[n][r] += __shfl_xor(cs[n][r], 1, 64);
      cs[n][r] += __shfl_xor(cs[n][r], 2, 64);
      cs[n][r] += __shfl_xor(cs[n][r], 4, 64);
      cs[n][r] += __shfl_xor(cs[n][r], 8, 64);
    }
  if (lo == 0) {
    float* Np = Npart + ((size_t)(b * 32 + tc)) * ATT_DIM;
#pragma unroll
    for (int n = 0; n < 4; ++n) {
      f32x4 v = {cs[n][0], cs[n][1], cs[n][2], cs[n][3]};
      *(f32x4*)(Np + wv * 64 + n * 16 + hi * 4) = v;
    }
  }
}

// K3: final combine per b: global M/Z from partials, attn from masked scores,
// ctx from weighted partials.
__global__ __launch_bounds__(512)
void final_kernel(const float* __restrict__ scores,
                  const float* __restrict__ partM,
                  const float* __restrict__ partZ,
                  const float* __restrict__ Npart,
                  float* __restrict__ ctx_out,    // d_out
                  float* __restrict__ attn_out) { // d_out + 16384
  __shared__ float sc_s[32];
  __shared__ float MZ[2];
  int b = blockIdx.x, tid = threadIdx.x;
  int lane = tid & 63;
  if (tid < 64) {
    float pm = (lane < 32) ? partM[b * 32 + lane] : -1e30f;
    float mx = pm;
#pragma unroll
    for (int d = 1; d < 64; d <<= 1) mx = fmaxf(mx, __shfl_xor(mx, d, 64));
    float e = (lane < 32) ? expf(pm - mx) : 0.f;
    float z = ((lane < 32) ? partZ[b * 32 + lane] : 0.f) * e;
#pragma unroll
    for (int d = 1; d < 64; d <<= 1) z += __shfl_xor(z, d, 64);
    if (lane < 32) sc_s[lane] = e;
    if (lane == 0) { MZ[0] = mx; MZ[1] = 1.f / z; }
  }
  __syncthreads();
  const float M = MZ[0], invZ = MZ[1];
  // attn
#pragma unroll
  for (int i = 0; i < 4; ++i) {
    int t = i * 512 + tid;
    attn_out[(size_t)b * T_DIM + t] = expf(scores[(size_t)b * T_DIM + t] - M) * invZ;
  }
  // ctx
  float acc = 0.f;
  const float* Np = Npart + (size_t)b * 32 * ATT_DIM;
#pragma unroll 8
  for (int tcc = 0; tcc < 32; ++tcc)
    acc = fmaf(sc_s[tcc], Np[tcc * ATT_DIM + tid], acc);
  ctx_out[(size_t)b * ATT_DIM + tid] = acc * invZ;
}

extern "C" void kernel_launch(void* const* d_in, const int* in_sizes, int n_in,
                              void* d_out, int out_size, void* d_ws, size_t ws_size,
                              hipStream_t stream) {
  const float* x   = (const float*)d_in[0];
  const float* spe = (const float*)d_in[1];
  const int*   len = (const int*)d_in[2];
  const float* Ws  = (const float*)d_in[4];
  const float* bs  = (const float*)d_in[5];
  const float* Wv  = (const float*)d_in[6];
  const float* bv  = (const float*)d_in[7];
  const float* Wp  = (const float*)d_in[8];
  const float* bp  = (const float*)d_in[9];
  float* out = (float*)d_out;  // [0,16384): context f32, [16384,81920): attn f32

  char* ws = (char*)d_ws;
  _Float16* WTf = (_Float16*)ws;                              // 2 MB packed frags
  float* q      = (float*)(ws + (2u << 20));                  // 64 KB
  float* scores = (float*)(ws + (2u << 20) + (64u << 10));    // 256 KB
  float* partM  = (float*)(ws + (2u << 20) + (320u << 10));   // 4 KB
  float* partZ  = (float*)(ws + (2u << 20) + (324u << 10));   // 4 KB
  float* Npart  = (float*)(ws + (2u << 20) + (328u << 10));   // 2 MB

  transpose_w_kernel<<<dim3(64), dim3(256), 0, stream>>>(Ws, Wv, WTf);
  query_kernel<<<dim3(32), dim3(256), 0, stream>>>(spe, Wp, bp, q);
  dual_gemm_kernel<<<dim3(1024), dim3(512), 0, stream>>>(
      x, WTf, bs, bv, q, len, scores, partM, partZ, Npart);
  final_kernel<<<dim3(32), dim3(512), 0, stream>>>(
      scores, partM, partZ, Npart, out, out + 16384);
}